// Round 1
// baseline (312.974 us; speedup 1.0000x reference)
//
#include <hip/hip_runtime.h>
#include <math.h>

// Problem constants (from reference setup_inputs)
constexpr int B = 16;
constexpr int S = 4096;
constexpr int F = 512;
constexpr int L = 64;        // output s-positions per thread
constexpr int HALO = 16;     // prefix window reach: k=31 -> p=15, need P[t-16]
constexpr int NV = L + 2 * HALO;  // 96 staged values per thread
constexpr int BLOCK = 256;   // threads per block; each thread owns one f

// out[b,t,f] = sum_i softmax(w)[i]/k_i * sum_{d=-p_i}^{p_i} x[b, clamp(t+d), f]
//
// Load-all-then-compute structure: each thread issues all NV=96 independent
// coalesced loads (one burst, ~24.6 KB in flight per wave), THEN does one
// in-place 96-long prefix sum and emits 64 outputs via prefix differences.
// sched_barrier(0) pins the load burst above the serial prefix chain so the
// compiler cannot register-minimize back into the old bursty load/wait/add
// pattern (previous version: 60 VGPRs, ~2.5 TB/s, latency-bound).
// __launch_bounds__(256, 4): 4 waves/SIMD target -> 128-VGPR budget.
__global__ __launch_bounds__(BLOCK, 4) void msavg_kernel(
    const float* __restrict__ x, const float* __restrict__ kw,
    float* __restrict__ out) {
  const int f  = blockIdx.x * BLOCK + threadIdx.x;   // 0..511
  const int t0 = blockIdx.y * L;                      // chunk start along S
  const int b  = blockIdx.z;

  // softmax over the 4 scale weights, folded with 1/k (uniform -> scalar regs)
  float w0 = kw[0], w1 = kw[1], w2 = kw[2], w3 = kw[3];
  float m  = fmaxf(fmaxf(w0, w1), fmaxf(w2, w3));
  float e0 = expf(w0 - m), e1 = expf(w1 - m), e2 = expf(w2 - m), e3 = expf(w3 - m);
  float inv = 1.0f / (e0 + e1 + e2 + e3);
  const float c3  = e0 * inv * (1.0f / 3.0f);
  const float c7  = e1 * inv * (1.0f / 7.0f);
  const float c15 = e2 * inv * (1.0f / 15.0f);
  const float c31 = e3 * inv * (1.0f / 31.0f);

  const float* xb = x   + ((size_t)b * S) * F + f;
  float*       ob = out + ((size_t)b * S) * F + f;

  // ---- Phase 1: one burst of NV independent loads (s = t0-16 .. t0+79) ----
  float v[NV];
  if (t0 - HALO >= 0 && t0 + L - 1 + HALO <= S - 1) {
    // interior fast path: no clamping, plain strided addresses
    const float* p0 = xb + (size_t)(t0 - HALO) * F;
#pragma unroll
    for (int j = 0; j < NV; ++j) v[j] = p0[(size_t)j * F];
  } else {
    // edge chunks (blockIdx.y == 0 or == S/L-1): clamp == replicate padding
#pragma unroll
    for (int j = 0; j < NV; ++j) {
      int s = t0 - HALO + j;
      s = s < 0 ? 0 : (s > S - 1 ? S - 1 : s);
      v[j] = xb[(size_t)s * F];
    }
  }
  // Keep every load above this point; compute below. Forces the full burst
  // to be issued before the first waitcnt-consuming prefix add.
  __builtin_amdgcn_sched_barrier(0);

  // ---- Phase 2: in-place prefix sum: v[j] = sum of clamped x up to s ----
  {
    float p = 0.0f;
#pragma unroll
    for (int j = 0; j < NV; ++j) { p += v[j]; v[j] = p; }
  }

  // ---- Phase 3: 64 outputs, t = t0 + i. P[s] == v[s - (t0-16)] ----
  // window sum k: P[t + p_k] - P[t - p_k - 1]
#pragma unroll
  for (int i = 0; i < L; ++i) {
    float o = c3  * (v[i + 17] - v[i + 14]) +   // k=3,  p=1
              c7  * (v[i + 19] - v[i + 12]) +   // k=7,  p=3
              c15 * (v[i + 23] - v[i + 8 ]) +   // k=15, p=7
              c31 * (v[i + 31] - v[i     ]);    // k=31, p=15
    // non-temporal store: output is never re-read; don't evict input halo
    // lines from L2/LLC (fetch is already < input size thanks to LLC reuse)
    __builtin_nontemporal_store(o, &ob[(size_t)(t0 + i) * F]);
  }
}

extern "C" void kernel_launch(void* const* d_in, const int* in_sizes, int n_in,
                              void* d_out, int out_size, void* d_ws, size_t ws_size,
                              hipStream_t stream) {
  const float* x  = (const float*)d_in[0];  // [16, 4096, 512] fp32
  const float* kw = (const float*)d_in[1];  // [4] fp32
  float* out = (float*)d_out;               // [16, 4096, 512] fp32
  (void)in_sizes; (void)n_in; (void)out_size; (void)d_ws; (void)ws_size;

  dim3 grid(F / BLOCK, S / L, B);  // (2, 64, 16) = 2048 blocks
  msavg_kernel<<<grid, BLOCK, 0, stream>>>(x, kw, out);
}

// Round 2
// 230.291 us; speedup vs baseline: 1.3590x; 1.3590x over previous
//
#include <hip/hip_runtime.h>
#include <math.h>

// Problem constants (from reference setup_inputs)
constexpr int B = 16;
constexpr int S = 4096;
constexpr int F = 512;
constexpr int L = 32;        // output s-positions per thread
constexpr int HALO = 16;     // prefix window reach: k=31 -> p=15, need P[t-16]
constexpr int NV = L + 2 * HALO;  // 64 staged values per thread
constexpr int BLOCK = 256;   // threads per block; each thread owns one f

// out[b,t,f] = sum_i softmax(w)[i]/k_i * sum_{d=-p_i}^{p_i} x[b, clamp(t+d), f]
//
// Load-all-then-compute: each thread issues NV=64 independent coalesced loads
// as one burst (16 KB in flight per wave), then one in-place 64-long prefix
// sum, then 32 outputs via prefix differences.
//
// Round-1 lesson: NV=96 + sched_barrier + __launch_bounds__(256,4) made the
// allocator spill the whole array to scratch (WRITE_SIZE 131->342 MB, the
// exact 201 MB array footprint). Fix: NV=64 (~78 live floats, fits ~90 VGPRs)
// and NO min-waves hint, so the allocator has the full 256-VGPR budget.
__global__ __launch_bounds__(BLOCK) void msavg_kernel(
    const float* __restrict__ x, const float* __restrict__ kw,
    float* __restrict__ out) {
  const int f  = blockIdx.x * BLOCK + threadIdx.x;   // 0..511
  const int t0 = blockIdx.y * L;                      // chunk start along S
  const int b  = blockIdx.z;

  // softmax over the 4 scale weights, folded with 1/k (uniform -> scalar regs)
  float w0 = kw[0], w1 = kw[1], w2 = kw[2], w3 = kw[3];
  float m  = fmaxf(fmaxf(w0, w1), fmaxf(w2, w3));
  float e0 = expf(w0 - m), e1 = expf(w1 - m), e2 = expf(w2 - m), e3 = expf(w3 - m);
  float inv = 1.0f / (e0 + e1 + e2 + e3);
  const float c3  = e0 * inv * (1.0f / 3.0f);
  const float c7  = e1 * inv * (1.0f / 7.0f);
  const float c15 = e2 * inv * (1.0f / 15.0f);
  const float c31 = e3 * inv * (1.0f / 31.0f);

  const float* xb = x   + ((size_t)b * S) * F + f;
  float*       ob = out + ((size_t)b * S) * F + f;

  // ---- Phase 1: one burst of NV independent loads (s = t0-16 .. t0+47) ----
  float v[NV];
  if (t0 - HALO >= 0 && t0 + L - 1 + HALO <= S - 1) {
    // interior fast path: no clamping, plain strided addresses
    const float* p0 = xb + (size_t)(t0 - HALO) * F;
#pragma unroll
    for (int j = 0; j < NV; ++j) v[j] = p0[(size_t)j * F];
  } else {
    // edge chunks (blockIdx.y == 0 or == S/L-1): clamp == replicate padding
#pragma unroll
    for (int j = 0; j < NV; ++j) {
      int s = t0 - HALO + j;
      s = s < 0 ? 0 : (s > S - 1 ? S - 1 : s);
      v[j] = xb[(size_t)s * F];
    }
  }
  // Pin the full load burst above the serial prefix chain: no instruction may
  // cross this point, so the compiler cannot register-minimize back into the
  // bursty load/wait/add pattern (round 0: ~60 VGPRs, 2.5 TB/s, latency-bound).
  __builtin_amdgcn_sched_barrier(0);

  // ---- Phase 2: in-place prefix sum: v[j] = sum of clamped x up to s ----
  {
    float p = 0.0f;
#pragma unroll
    for (int j = 0; j < NV; ++j) { p += v[j]; v[j] = p; }
  }

  // ---- Phase 3: 32 outputs, t = t0 + i. P[s] == v[s - (t0-16)] ----
  // window sum k: P[t + p_k] - P[t - p_k - 1]
#pragma unroll
  for (int i = 0; i < L; ++i) {
    float o = c3  * (v[i + 17] - v[i + 14]) +   // k=3,  p=1
              c7  * (v[i + 19] - v[i + 12]) +   // k=7,  p=3
              c15 * (v[i + 23] - v[i + 8 ]) +   // k=15, p=7
              c31 * (v[i + 31] - v[i     ]);    // k=31, p=15
    // non-temporal store: output is never re-read; don't evict input halo
    __builtin_nontemporal_store(o, &ob[(size_t)(t0 + i) * F]);
  }
}

extern "C" void kernel_launch(void* const* d_in, const int* in_sizes, int n_in,
                              void* d_out, int out_size, void* d_ws, size_t ws_size,
                              hipStream_t stream) {
  const float* x  = (const float*)d_in[0];  // [16, 4096, 512] fp32
  const float* kw = (const float*)d_in[1];  // [4] fp32
  float* out = (float*)d_out;               // [16, 4096, 512] fp32
  (void)in_sizes; (void)n_in; (void)out_size; (void)d_ws; (void)ws_size;

  dim3 grid(F / BLOCK, S / L, B);  // (2, 128, 16) = 4096 blocks
  msavg_kernel<<<grid, BLOCK, 0, stream>>>(x, kw, out);
}